// Round 4
// baseline (354.308 us; speedup 1.0000x reference)
//
#include <hip/hip_runtime.h>
#include <hip/hip_bf16.h>
#include <math.h>

#define S_TOK 8192
#define M_DIM 1024
#define E_NUM 8
#define F_DIM 4096
#define CAP   1024

typedef short short8 __attribute__((ext_vector_type(8)));
typedef float f32x4 __attribute__((ext_vector_type(4)));
typedef unsigned short ushortx4 __attribute__((ext_vector_type(4)));

__device__ inline unsigned short f2bf(float f) {
    union { float f; unsigned int u; } v; v.f = f;
    unsigned int r = v.u + 0x7fffu + ((v.u >> 16) & 1u);
    return (unsigned short)(r >> 16);
}

// gelu(x) = 0.5 x (1 + tanh(y)), y = c(x + 0.044715 x^3) = x*e/(e+1), e=exp(2y)
__device__ inline float gelu_fast(float x) {
    float y = 0.7978845608028654f * (x + 0.044715f * x * x * x);
    if (y > 40.f) return x;
    float e = exp2f(2.8853900817779268f * y);
    return x * e / (e + 1.0f);
}

__device__ inline void gl_lds16(const void* g, void* l) {
    __builtin_amdgcn_global_load_lds(
        (const __attribute__((address_space(1))) unsigned int*)g,
        (__attribute__((address_space(3))) unsigned int*)l, 16, 0, 0);
}

// ---------------- gating ----------------
__global__ __launch_bounds__(256) void gating_kernel(
    const float* __restrict__ x, const float* __restrict__ wg,
    int* __restrict__ idx, float* __restrict__ gate)
{
    int wid = threadIdx.x >> 6;
    int lane = threadIdx.x & 63;
    int s = blockIdx.x * 4 + wid;
    const float* xs = x + (size_t)s * M_DIM;

    double acc[E_NUM];
#pragma unroll
    for (int e = 0; e < E_NUM; e++) acc[e] = 0.0;

    for (int i = lane; i < M_DIM; i += 64) {
        float xv = xs[i];
        float4 wa = *(const float4*)(wg + (size_t)i * E_NUM);
        float4 wb = *(const float4*)(wg + (size_t)i * E_NUM + 4);
        acc[0] += (double)xv * (double)wa.x;
        acc[1] += (double)xv * (double)wa.y;
        acc[2] += (double)xv * (double)wa.z;
        acc[3] += (double)xv * (double)wa.w;
        acc[4] += (double)xv * (double)wb.x;
        acc[5] += (double)xv * (double)wb.y;
        acc[6] += (double)xv * (double)wb.z;
        acc[7] += (double)xv * (double)wb.w;
    }
#pragma unroll
    for (int e = 0; e < E_NUM; e++) {
        double v = acc[e];
        for (int o = 32; o > 0; o >>= 1) v += __shfl_down(v, o, 64);
        acc[e] = v;
    }
    if (lane == 0) {
        double mx = acc[0]; int am = 0;
#pragma unroll
        for (int e = 1; e < E_NUM; e++) {
            if (acc[e] > mx) { mx = acc[e]; am = e; }
        }
        double se = 0.0;
#pragma unroll
        for (int e = 0; e < E_NUM; e++) se += exp(acc[e] - mx);
        idx[s] = am;
        gate[s] = (float)(1.0 / se);
    }
}

// ---------------- scan: token-order slot assignment ----------------
__global__ __launch_bounds__(1024) void scan_build(
    const int* __restrict__ idx, int* __restrict__ srcmap)
{
    __shared__ unsigned int sc[2][4][1024];
    int t = threadIdx.x;

    for (int i = t; i < E_NUM * CAP; i += 1024) srcmap[i] = -1;

    int eid[8];
    unsigned int cnt[E_NUM];
#pragma unroll
    for (int e = 0; e < E_NUM; e++) cnt[e] = 0;
#pragma unroll
    for (int i = 0; i < 8; i++) {
        int e = idx[t * 8 + i];
        eid[i] = e;
        cnt[e]++;
    }
    unsigned int pk[4];
#pragma unroll
    for (int i = 0; i < 4; i++) pk[i] = cnt[2 * i] | (cnt[2 * i + 1] << 16);
#pragma unroll
    for (int i = 0; i < 4; i++) sc[0][i][t] = pk[i];

    int buf = 0;
    for (int ofs = 1; ofs < 1024; ofs <<= 1) {
        __syncthreads();
        unsigned int v[4];
#pragma unroll
        for (int i = 0; i < 4; i++) {
            v[i] = sc[buf][i][t] + ((t >= ofs) ? sc[buf][i][t - ofs] : 0u);
            sc[buf ^ 1][i][t] = v[i];
        }
        buf ^= 1;
    }
    __syncthreads();
    unsigned int pos[E_NUM];
#pragma unroll
    for (int e = 0; e < E_NUM; e++) {
        unsigned int incl = (sc[buf][e >> 1][t] >> ((e & 1) * 16)) & 0xffffu;
        pos[e] = incl - cnt[e];
    }
#pragma unroll
    for (int i = 0; i < 8; i++) {
        int e = eid[i];
        unsigned int p = pos[e]++;
        if (p < CAP) srcmap[e * CAP + p] = t * 8 + i;
    }
}

// ---------------- dispatch: gather rows -> bf16 A1 [E*C][M] ----------------
__global__ __launch_bounds__(256) void dispatch_kernel(
    const float* __restrict__ x, const int* __restrict__ srcmap,
    unsigned short* __restrict__ A1)
{
    int slot = blockIdx.x;
    int s = srcmap[slot];
    int t = threadIdx.x;
    ushortx4 o;
    if (s >= 0) {
        float4 v = ((const float4*)(x + (size_t)s * M_DIM))[t];
        o[0] = f2bf(v.x); o[1] = f2bf(v.y); o[2] = f2bf(v.z); o[3] = f2bf(v.w);
    } else {
        o[0] = 0; o[1] = 0; o[2] = 0; o[3] = 0;
    }
    ((ushortx4*)(A1 + (size_t)slot * M_DIM))[t] = o;
}

// ---------------- transpose + cvt ----------------
__global__ __launch_bounds__(256) void transpose_cvt(
    const float* __restrict__ in, unsigned short* __restrict__ out, int R, int Cc)
{
    __shared__ float tile[32][33];
    int e = blockIdx.z;
    int br = blockIdx.y * 32, bc = blockIdx.x * 32;
    const float* ine = in + (size_t)e * R * Cc;
    unsigned short* oute = out + (size_t)e * R * Cc;
    int tx = threadIdx.x, ty = threadIdx.y;
#pragma unroll
    for (int i = 0; i < 32; i += 8)
        tile[ty + i][tx] = ine[(size_t)(br + ty + i) * Cc + (bc + tx)];
    __syncthreads();
#pragma unroll
    for (int i = 0; i < 32; i += 8)
        oute[(size_t)(bc + ty + i) * R + (br + tx)] = f2bf(tile[tx][ty + i]);
}

// ---------------- deep BK=64 double-buffered bf16 MFMA GEMM ----------------
// 8 waves (2Mx4N), BN=256. LDS per K-tile: A/B stored as [ks][rows][64B] halves
// (round-3's measured conflict-free geometry). 2-phase m248 template:
// STAGE(next) first, then ds_read+64 MFMA/wave, one vmcnt(0)+barrier per tile.
// MODE 0 (GEMM1): BM=256, K=1024, NB=4096: OutH = bf16(gelu(acc+bias)), LDS-repacked stores.
// MODE 1 (GEMM2): BM=128, K=4096, NB=1024: out[s] = gate[s]*(acc+bias), row-scatter.
template <int MODE>
__global__ __launch_bounds__(512) void gemm256(
    const unsigned short* __restrict__ A, const unsigned short* __restrict__ B,
    const float* __restrict__ bias, unsigned short* __restrict__ OutH,
    float* __restrict__ OutF, const int* __restrict__ srcmap,
    const float* __restrict__ gate)
{
    constexpr int K    = (MODE == 0) ? 1024 : 4096;
    constexpr int NB   = (MODE == 0) ? 4096 : 1024;
    constexpr int BM   = (MODE == 0) ? 256 : 128;
    constexpr int NT   = K / 64;
    constexpr int NWG  = (MODE == 0) ? 512 : 256;
    constexpr int AI   = BM / 64;        // A staging instrs per wave (4 or 2)
    constexpr int MI   = BM / 32;        // m-fragments per wave (8 or 4)
    constexpr int ASLOT = BM * 64;       // ushorts per A slot ([2ks][BM][32])
    constexpr int BBASE = BM * 128;      // ushort offset of B region (2 A slots)

    __shared__ __align__(16) unsigned short LDS[BBASE + 32768];

    int bid = blockIdx.x;
    int swz = (bid & 7) * (NWG / 8) + (bid >> 3);   // XCD-aware, bijective (NWG%8==0)
    int e, tm, tn;
    if (MODE == 0) { e = swz >> 6; int r = swz & 63; tm = r >> 4; tn = r & 15; }
    else           { e = swz >> 5; int r = swz & 31; tm = r >> 2; tn = r & 3; }

    const unsigned short* Ae = A + ((size_t)e * CAP + (size_t)tm * BM) * K;
    const unsigned short* Be = B + ((size_t)e * NB + (size_t)tn * 256) * K;

    int tid = threadIdx.x, w = tid >> 6, lane = tid & 63;
    int wm = w >> 2, wn = w & 3;
    int fr = lane & 15, kq = lane >> 4;

    // ---- staging addresses (pre-swizzled global source, linear LDS dest) ----
    const unsigned short* srcA[4]; int dA[4];
#pragma unroll
    for (int i = 0; i < AI; i++) {
        int ks = i & 1;
        int rb = (AI == 4) ? (w * 32 + (i >> 1) * 16) : (w * 16);
        int row = rb + (lane >> 2);
        int logc = (lane & 3) ^ ((row >> 1) & 3);
        srcA[i] = Ae + (size_t)row * K + ks * 32 + logc * 8;
        dA[i] = ks * (BM * 32) + rb * 32;
    }
    const unsigned short* srcB[4]; int dB[4];
#pragma unroll
    for (int i = 0; i < 4; i++) {
        int ks = i & 1;
        int rb = w * 32 + (i >> 1) * 16;
        int row = rb + (lane >> 2);
        int logc = (lane & 3) ^ ((row >> 1) & 3);
        srcB[i] = Be + (size_t)row * K + ks * 32 + logc * 8;
        dB[i] = ks * 8192 + rb * 32;
    }

#define STAGE(sl, t_) do { int k0_ = (t_) * 64;                                   \
    gl_lds16(srcA[0] + k0_, &LDS[(sl) * ASLOT + dA[0]]);                          \
    gl_lds16(srcA[1] + k0_, &LDS[(sl) * ASLOT + dA[1]]);                          \
    if (AI == 4) {                                                                \
        gl_lds16(srcA[2] + k0_, &LDS[(sl) * ASLOT + dA[2]]);                      \
        gl_lds16(srcA[3] + k0_, &LDS[(sl) * ASLOT + dA[3]]);                      \
    }                                                                             \
    gl_lds16(srcB[0] + k0_, &LDS[BBASE + (sl) * 16384 + dB[0]]);                  \
    gl_lds16(srcB[1] + k0_, &LDS[BBASE + (sl) * 16384 + dB[1]]);                  \
    gl_lds16(srcB[2] + k0_, &LDS[BBASE + (sl) * 16384 + dB[2]]);                  \
    gl_lds16(srcB[3] + k0_, &LDS[BBASE + (sl) * 16384 + dB[3]]);                  \
} while (0)

    // ---- read addressing (same conflict-free swizzle as round 3, per ks-half) ----
    int aoff = (kq ^ ((fr >> 1) & 3)) * 8;            // swizzled 16B chunk in 64B row
    int arowb = (wm * (BM / 2) + fr) * 32 + aoff;     // + mi*512 + ks*(BM*32) + slot*ASLOT
    int browb = BBASE + (wn * 64 + fr) * 32 + aoff;   // + ni*512 + ks*8192 + slot*16384

    f32x4 acc[MI][4];
#pragma unroll
    for (int i = 0; i < MI; i++)
#pragma unroll
        for (int j = 0; j < 4; j++) acc[i][j] = (f32x4){0.f, 0.f, 0.f, 0.f};

    STAGE(0, 0);
    asm volatile("s_waitcnt vmcnt(0)" ::: "memory");
    __builtin_amdgcn_s_barrier();

    int cur = 0;
    for (int t = 0; t < NT; ++t) {
        if (t + 1 < NT) STAGE(cur ^ 1, t + 1);       // issue next-tile loads FIRST

        int as = cur * ASLOT, bs = cur * 16384;
        short8 b[4][2];
#pragma unroll
        for (int ni = 0; ni < 4; ni++) {
            b[ni][0] = *(const short8*)&LDS[bs + browb + ni * 512];
            b[ni][1] = *(const short8*)&LDS[bs + browb + ni * 512 + 8192];
        }
#pragma unroll
        for (int mh = 0; mh < MI / 4; ++mh) {
            short8 a[4][2];
#pragma unroll
            for (int m2 = 0; m2 < 4; m2++) {
                a[m2][0] = *(const short8*)&LDS[as + arowb + (mh * 4 + m2) * 512];
                a[m2][1] = *(const short8*)&LDS[as + arowb + (mh * 4 + m2) * 512 + BM * 32];
            }
            __builtin_amdgcn_s_setprio(1);
#pragma unroll
            for (int m2 = 0; m2 < 4; m2++)
#pragma unroll
                for (int ni = 0; ni < 4; ni++) {
                    acc[mh * 4 + m2][ni] = __builtin_amdgcn_mfma_f32_16x16x32_bf16(
                        a[m2][0], b[ni][0], acc[mh * 4 + m2][ni], 0, 0, 0);
                    acc[mh * 4 + m2][ni] = __builtin_amdgcn_mfma_f32_16x16x32_bf16(
                        a[m2][1], b[ni][1], acc[mh * 4 + m2][ni], 0, 0, 0);
                }
            __builtin_amdgcn_s_setprio(0);
        }

        if (t + 1 < NT) asm volatile("s_waitcnt vmcnt(0)" ::: "memory");
        __builtin_amdgcn_s_barrier();
        cur ^= 1;
    }
#undef STAGE

    int cbase = tn * 256 + wn * 64;
    if (MODE == 0) {
        // epilogue: gelu+bias -> LDS repack (256x256 bf16 = whole 128KB) -> 16B stores
        float bv[4];
#pragma unroll
        for (int ni = 0; ni < 4; ni++) bv[ni] = bias[e * NB + cbase + ni * 16 + fr];
#pragma unroll
        for (int mi = 0; mi < MI; mi++) {
#pragma unroll
            for (int j = 0; j < 4; j++) {
                int lrow = wm * 128 + mi * 16 + kq * 4 + j;
#pragma unroll
                for (int ni = 0; ni < 4; ni++) {
                    int lcol = wn * 64 + ni * 16 + fr;
                    LDS[lrow * 256 + lcol] = f2bf(gelu_fast(acc[mi][ni][j] + bv[ni]));
                }
            }
        }
        __syncthreads();
        int row = tid >> 1, seg = tid & 1;
        const short8* sp = (const short8*)&LDS[row * 256 + seg * 128];
        short8* dp = (short8*)&OutH[((size_t)(e * CAP + tm * 256 + row)) * (size_t)NB
                                    + tn * 256 + seg * 128];
#pragma unroll
        for (int i = 0; i < 16; i++) dp[i] = sp[i];
    } else {
        // epilogue: fused combine: out[s] = gate[s]*(acc + b2), row scatter
        float bv[4];
#pragma unroll
        for (int ni = 0; ni < 4; ni++) bv[ni] = bias[e * NB + cbase + ni * 16 + fr];
#pragma unroll
        for (int mi = 0; mi < MI; mi++) {
#pragma unroll
            for (int j = 0; j < 4; j++) {
                int r = tm * BM + wm * (BM / 2) + mi * 16 + kq * 4 + j;
                int s = srcmap[e * CAP + r];
                if (s < 0) continue;
                float g = gate[s];
                float* ob = OutF + (size_t)s * NB + cbase;
#pragma unroll
                for (int ni = 0; ni < 4; ni++)
                    ob[ni * 16 + fr] = g * (acc[mi][ni][j] + bv[ni]);
            }
        }
    }
}

extern "C" void kernel_launch(void* const* d_in, const int* in_sizes, int n_in,
                              void* d_out, int out_size, void* d_ws, size_t ws_size,
                              hipStream_t stream) {
    const float* x  = (const float*)d_in[0];  // [S, M]
    const float* wg = (const float*)d_in[1];  // [M, E]
    const float* w1 = (const float*)d_in[2];  // [E, M, F]
    const float* b1 = (const float*)d_in[3];  // [E, F]
    const float* w2 = (const float*)d_in[4];  // [E, F, M]
    const float* b2 = (const float*)d_in[5];  // [E, M]
    float* out = (float*)d_out;

    char* ws = (char*)d_ws;
    unsigned short* A1  = (unsigned short*)(ws);                       // 16 MiB [E*C][M]
    unsigned short* W1T = (unsigned short*)(ws + (size_t)(16u << 20)); // 64 MiB [E][F][M]
    unsigned short* W2T = (unsigned short*)(ws + (size_t)(80u << 20)); // 64 MiB [E][M][F]
    unsigned short* H   = (unsigned short*)(ws + (size_t)(144u << 20));// 64 MiB [E][C][F]
    int*   idx  = (int*)(ws + (size_t)(208u << 20));
    float* gate = (float*)(ws + (size_t)(208u << 20) + 32768);
    int*   srcm = (int*)(ws + (size_t)(208u << 20) + 65536);

    hipMemsetAsync(d_out, 0, (size_t)S_TOK * M_DIM * sizeof(float), stream);

    gating_kernel<<<S_TOK / 4, 256, 0, stream>>>(x, wg, idx, gate);
    scan_build<<<1, 1024, 0, stream>>>(idx, srcm);
    dispatch_kernel<<<E_NUM * CAP, 256, 0, stream>>>(x, srcm, A1);
    transpose_cvt<<<dim3(F_DIM / 32, M_DIM / 32, E_NUM), dim3(32, 8), 0, stream>>>(
        w1, W1T, M_DIM, F_DIM);
    transpose_cvt<<<dim3(M_DIM / 32, F_DIM / 32, E_NUM), dim3(32, 8), 0, stream>>>(
        w2, W2T, F_DIM, M_DIM);

    // GEMM1: H = gelu(A1 @ w1 + b1)  [E][1024][4096], K=1024; 512 blocks (256x256 tiles)
    gemm256<0><<<512, 512, 0, stream>>>(A1, W1T, b1, H, nullptr, nullptr, nullptr);

    // GEMM2: out[s] = gate[s]*(H @ w2 + b2)  K=4096; 256 blocks (128x256 tiles), fused combine
    gemm256<1><<<256, 512, 0, stream>>>(H, W2T, b2, nullptr, out, srcm, gate);
}